// Round 3
// baseline (630.627 us; speedup 1.0000x reference)
//
#include <hip/hip_runtime.h>
#include <hip/hip_bf16.h>
#include <math.h>

typedef __hip_bfloat16 bf16;
typedef __attribute__((ext_vector_type(8))) short v8s;   // 8 x bf16
typedef __attribute__((ext_vector_type(4))) float v4f;

#define HD 96
#define WD 96
#define HW 9216            // 96*96
#define BATCH 4

// ws float-offset layout
#define OFF_WR    0        // 16x64  scaled w_reduce
#define OFF_CR    1024     // 16     reduce-BN additive
#define OFF_WSP   1040     // 196x16 w_span
#define OFF_BSP   4176     // 196    b_span
#define OFF_SI    4372     // 64     bn_i scale
#define OFF_CI    4436     // 64     bn_i additive
#define OFF_BIAS  4500     // 128    combined bias (fp32)
#define WFRAG_BYTE 18512   // bf16 W MFMA A-fragments: [mt8][ks4][lane64][j8] = 16384 bf16 (32KB)
#define X1_BYTE   51328    // bf16 x1 buffer, BATCH*64*HW elems (4.72 MB)

__device__ __forceinline__ float geluf(float v) {
    return 0.5f * v * (1.0f + erff(v * 0.7071067811865475f));
}

// ---------------- K0: fold BN params (64 blocks) ---------------------------
__global__ __launch_bounds__(256) void k_fold(
    const float* __restrict__ wred,
    const float* __restrict__ gr, const float* __restrict__ br,
    const float* __restrict__ mr, const float* __restrict__ vr,
    const float* __restrict__ wspan, const float* __restrict__ bspan,
    const float* __restrict__ gi, const float* __restrict__ bi,
    const float* __restrict__ mi, const float* __restrict__ vi,
    const float* __restrict__ wconv,
    const float* __restrict__ gc, const float* __restrict__ bc,
    const float* __restrict__ mc, const float* __restrict__ vc,
    const float* __restrict__ wmap, const float* __restrict__ bmap,
    const float* __restrict__ gm, const float* __restrict__ bm,
    const float* __restrict__ mmn, const float* __restrict__ vm,
    float* __restrict__ wsf, bf16* __restrict__ wfrag)
{
    const int gt = blockIdx.x * 256 + threadIdx.x;   // 0..16383

    if (gt < 1024) {
        int r = gt >> 6;
        float sr = gr[r] * rsqrtf(vr[r] + 1e-5f);
        wsf[OFF_WR + gt] = sr * wred[gt];
    }
    if (gt < 16) {
        float sr = gr[gt] * rsqrtf(vr[gt] + 1e-5f);
        wsf[OFF_CR + gt] = br[gt] - mr[gt] * sr;
    }
    if (gt < 3136) wsf[OFF_WSP + gt] = wspan[gt];
    if (gt < 196)  wsf[OFF_BSP + gt] = bspan[gt];
    if (gt < 64) {
        float si = gi[gt] * rsqrtf(vi[gt] + 1e-5f);
        wsf[OFF_SI + gt] = si;
        wsf[OFF_CI + gt] = bi[gt] - mi[gt] * si;
    }
    if (gt < 128) {
        float sc = gc[gt] * rsqrtf(vc[gt] + 1e-5f);
        float sm = gm[gt] * rsqrtf(vm[gt] + 1e-5f);
        wsf[OFF_BIAS + gt] = (bc[gt] - mc[gt] * sc)
                           + sm * bmap[gt]
                           + (bm[gt] - mmn[gt] * sm);
    }
    // W MFMA A-fragments: lane l of the fragment holds W[mt*16+(l&15)][ks*32+(l>>4)*8+j]
    {
        int j    = gt & 7;
        int lane = (gt >> 3) & 63;
        int ks   = (gt >> 9) & 3;
        int mt   = gt >> 11;
        int m = mt * 16 + (lane & 15);
        int k = ks * 32 + (lane >> 4) * 8 + j;
        float v;
        if (k < 64) {
            float sc = gc[m] * rsqrtf(vc[m] + 1e-5f);
            v = sc * wconv[m * 64 + k];
        } else {
            float sm = gm[m] * rsqrtf(vm[m] + 1e-5f);
            v = sm * wmap[m * 64 + (k - 64)];
        }
        wfrag[gt] = __float2bfloat16(v);
    }
}

// ---------------- K1: involution + bn_i + GELU -> x1 (bf16 in ws) ----------
// Block: 256 threads = 64 pixels (8x8 tile) x 4 groups. Grid (12,12,4).
// LDS x layout: xs4[(cb*196 + pos)*4 + ci], cb = c/4, ci = c%4 -> b128 reads.
__global__ __launch_bounds__(256, 2) void k_inv(
    const float* __restrict__ x, const float* __restrict__ wsf,
    bf16* __restrict__ x1)
{
    __shared__ float xs4[16 * 196 * 4];   // 50176 B
    __shared__ float ts[64 * 20];         // 5120 B

    const int tid = threadIdx.x;
    const int b  = blockIdx.z;
    const int ty = blockIdx.y * 8, tx = blockIdx.x * 8;

    const float* xb = x + (size_t)b * 64 * HW;
    for (int it = tid; it < 3136; it += 256) {        // it = cb*196 + pos
        int cb = it / 196, pos = it % 196;
        int py = pos / 14, px = pos % 14;
        int gy = ty + py - 3, gx = tx + px - 3;
        v4f v = (v4f){0.f, 0.f, 0.f, 0.f};
        if (gy >= 0 && gy < HD && gx >= 0 && gx < WD) {
            const float* p = xb + (size_t)(cb * 4) * HW + gy * WD + gx;
            v[0] = p[0]; v[1] = p[HW]; v[2] = p[2 * HW]; v[3] = p[3 * HW];
        }
        *(v4f*)&xs4[it * 4] = v;
    }
    __syncthreads();

    const int p = tid & 63;
    const int q = __builtin_amdgcn_readfirstlane(tid >> 6);  // wave-uniform group
    const int py0 = p >> 3, px0 = p & 7;
    const int center = (py0 + 3) * 14 + (px0 + 3);

    // t[q*4 .. q*4+3] for this pixel (weights: wave-uniform scalar loads)
    float t4[4];
    #pragma unroll
    for (int r = 0; r < 4; ++r) t4[r] = wsf[OFF_CR + q * 4 + r];
    #pragma unroll
    for (int cb = 0; cb < 16; ++cb) {
        v4f xv = *(const v4f*)&xs4[(cb * 196 + center) * 4];
        #pragma unroll
        for (int ci = 0; ci < 4; ++ci) {
            float xc = xv[ci];
            #pragma unroll
            for (int r = 0; r < 4; ++r)
                t4[r] += wsf[OFF_WR + (q * 4 + r) * 64 + cb * 4 + ci] * xc;
        }
    }
    {
        v4f tw;
        #pragma unroll
        for (int r = 0; r < 4; ++r) tw[r] = fmaxf(t4[r], 0.0f);
        *(v4f*)&ts[p * 20 + q * 4] = tw;
    }
    __syncthreads();

    float tr[16];
    #pragma unroll
    for (int k4 = 0; k4 < 4; ++k4) {
        v4f tv = *(const v4f*)&ts[p * 20 + k4 * 4];
        #pragma unroll
        for (int r = 0; r < 4; ++r) tr[k4 * 4 + r] = tv[r];
    }

    const int g = q;
    const int cb0 = g * 4;
    float inv[16];
    #pragma unroll
    for (int i = 0; i < 16; ++i) inv[i] = 0.0f;

    #pragma unroll
    for (int i = 0; i < 7; ++i) {
        const int rowb = (py0 + i) * 14 + px0;
        #pragma unroll
        for (int jj = 0; jj < 7; ++jj) {
            const int row = g * 49 + i * 7 + jj;
            float kv = wsf[OFF_BSP + row];
            #pragma unroll
            for (int r = 0; r < 16; ++r) kv += wsf[OFF_WSP + row * 16 + r] * tr[r];
            const int nb = rowb + jj;
            #pragma unroll
            for (int u = 0; u < 4; ++u) {
                v4f xv = *(const v4f*)&xs4[((cb0 + u) * 196 + nb) * 4];
                inv[u * 4 + 0] += kv * xv[0];
                inv[u * 4 + 1] += kv * xv[1];
                inv[u * 4 + 2] += kv * xv[2];
                inv[u * 4 + 3] += kv * xv[3];
            }
        }
    }

    bf16* x1b = x1 + (size_t)b * 64 * HW + (ty + py0) * WD + (tx + px0);
    #pragma unroll
    for (int c16 = 0; c16 < 16; ++c16) {
        int c = g * 16 + c16;
        float v = inv[c16] * wsf[OFF_SI + c] + wsf[OFF_CI + c];
        x1b[(size_t)c * HW] = __float2bfloat16(geluf(v));
    }
}

// ---------------- K2: 128x128 pointwise GEMM + GELU via MFMA ---------------
// Block: 256 threads = 4 waves; 64-px tile. Each wave: 16 px strip, M=128.
#define ZPAD 136
__global__ __launch_bounds__(256) void k_out(
    const float* __restrict__ x, const bf16* __restrict__ x1,
    const float* __restrict__ wsf, const bf16* __restrict__ wfrag,
    float* __restrict__ out)
{
    __shared__ bf16 zl[64 * ZPAD];   // [px][ch] transposed Z tile, 17408 B

    const int tid  = threadIdx.x;
    const int lane = tid & 63;
    const int cw   = tid >> 6;
    const int tile = blockIdx.x * 64;      // global pixel base (never straddles b)
    const int b    = tile / HW;
    const int hw0  = tile % HW;

    const bf16*  x1b = x1 + (size_t)b * 64 * HW + hw0;
    const float* xb  = x  + (size_t)b * 64 * HW + hw0;

    // stage Z = concat(x1, x) transposed into LDS as bf16
    #pragma unroll
    for (int r = 0; r < 32; ++r) {
        int ch = r * 4 + cw;               // 0..127, each exactly once per block
        bf16 v;
        if (ch < 64) v = x1b[(size_t)ch * HW + lane];
        else         v = __float2bfloat16(xb[(size_t)(ch - 64) * HW + lane]);
        zl[lane * ZPAD + ch] = v;
    }
    __syncthreads();

    const int w    = cw;                   // wave id
    const int n    = lane & 15;
    const int quad = lane >> 4;
    const int pxl  = w * 16 + n;           // pixel within tile

    v4f acc[8];
    #pragma unroll
    for (int mt = 0; mt < 8; ++mt) acc[mt] = (v4f){0.f, 0.f, 0.f, 0.f};

    const v8s* wf = (const v8s*)wfrag;
    #pragma unroll
    for (int ks = 0; ks < 4; ++ks) {
        v8s bfrag = *(const v8s*)&zl[pxl * ZPAD + ks * 32 + quad * 8];
        #pragma unroll
        for (int mt = 0; mt < 8; ++mt) {
            v8s afrag = wf[(mt * 4 + ks) * 64 + lane];
            acc[mt] = __builtin_amdgcn_mfma_f32_16x16x32_bf16(afrag, bfrag, acc[mt], 0, 0, 0);
        }
    }

    const int hw = hw0 + pxl;
    #pragma unroll
    for (int mt = 0; mt < 8; ++mt) {
        int m0 = mt * 16 + quad * 4;
        v4f bs = *(const v4f*)&wsf[OFF_BIAS + m0];
        #pragma unroll
        for (int reg = 0; reg < 4; ++reg) {
            float v = acc[mt][reg] + bs[reg];
            out[((size_t)(b * 128 + m0 + reg)) * HW + hw] = geluf(v);
        }
    }
}

// ---------------------------------------------------------------------------
extern "C" void kernel_launch(void* const* d_in, const int* in_sizes, int n_in,
                              void* d_out, int out_size, void* d_ws, size_t ws_size,
                              hipStream_t stream)
{
    const float* x     = (const float*)d_in[0];
    const float* wred  = (const float*)d_in[1];
    const float* gr    = (const float*)d_in[2];
    const float* br    = (const float*)d_in[3];
    const float* mr    = (const float*)d_in[4];
    const float* vr    = (const float*)d_in[5];
    const float* wspan = (const float*)d_in[6];
    const float* bspan = (const float*)d_in[7];
    const float* gi    = (const float*)d_in[8];
    const float* bi    = (const float*)d_in[9];
    const float* mi    = (const float*)d_in[10];
    const float* vi    = (const float*)d_in[11];
    const float* wconv = (const float*)d_in[12];
    const float* gc    = (const float*)d_in[13];
    const float* bc    = (const float*)d_in[14];
    const float* mc    = (const float*)d_in[15];
    const float* vc    = (const float*)d_in[16];
    const float* wmap  = (const float*)d_in[17];
    const float* bmap  = (const float*)d_in[18];
    const float* gm    = (const float*)d_in[19];
    const float* bm    = (const float*)d_in[20];
    const float* mmn   = (const float*)d_in[21];
    const float* vm    = (const float*)d_in[22];

    float* wsf   = (float*)d_ws;
    bf16*  wfrag = (bf16*)((char*)d_ws + WFRAG_BYTE);
    bf16*  x1    = (bf16*)((char*)d_ws + X1_BYTE);
    float* out   = (float*)d_out;

    hipLaunchKernelGGL(k_fold, dim3(64), dim3(256), 0, stream,
                       wred, gr, br, mr, vr, wspan, bspan, gi, bi, mi, vi,
                       wconv, gc, bc, mc, vc, wmap, bmap, gm, bm, mmn, vm,
                       wsf, wfrag);
    hipLaunchKernelGGL(k_inv, dim3(12, 12, BATCH), dim3(256), 0, stream, x, wsf, x1);
    hipLaunchKernelGGL(k_out, dim3((BATCH * HW) / 64), dim3(256), 0, stream,
                       x, x1, wsf, wfrag, out);
}

// Round 4
// 160.043 us; speedup vs baseline: 3.9404x; 3.9404x over previous
//
#include <hip/hip_runtime.h>
#include <hip/hip_bf16.h>
#include <math.h>

typedef __hip_bfloat16 bf16;
typedef __attribute__((ext_vector_type(8))) short v8s;   // 8 x bf16
typedef __attribute__((ext_vector_type(4))) float v4f;

#define HD 96
#define WD 96
#define HW 9216            // 96*96
#define BATCH 4

// ws float-offset layout
#define OFF_WR    0        // 16x64  scaled w_reduce
#define OFF_CR    1024     // 16     reduce-BN additive
#define OFF_WSP   1040     // 196x16 w_span
#define OFF_BSP   4176     // 196    b_span
#define OFF_SI    4372     // 64     bn_i scale
#define OFF_CI    4436     // 64     bn_i additive
#define OFF_BIAS  4500     // 128    combined bias (fp32)
#define WFRAG_BYTE 18512   // bf16 W MFMA A-fragments: [mt8][ks4][lane64][j8] (32KB)
#define X1_BYTE   51328    // bf16 x1 buffer, BATCH*64*HW elems (4.72 MB)

__device__ __forceinline__ float geluf(float v) {
    return 0.5f * v * (1.0f + erff(v * 0.7071067811865475f));
}

// ---------------- K0: fold BN params (64 blocks) ---------------------------
__global__ __launch_bounds__(256) void k_fold(
    const float* __restrict__ wred,
    const float* __restrict__ gr, const float* __restrict__ br,
    const float* __restrict__ mr, const float* __restrict__ vr,
    const float* __restrict__ wspan, const float* __restrict__ bspan,
    const float* __restrict__ gi, const float* __restrict__ bi,
    const float* __restrict__ mi, const float* __restrict__ vi,
    const float* __restrict__ wconv,
    const float* __restrict__ gc, const float* __restrict__ bc,
    const float* __restrict__ mc, const float* __restrict__ vc,
    const float* __restrict__ wmap, const float* __restrict__ bmap,
    const float* __restrict__ gm, const float* __restrict__ bm,
    const float* __restrict__ mmn, const float* __restrict__ vm,
    float* __restrict__ wsf, bf16* __restrict__ wfrag)
{
    const int gt = blockIdx.x * 256 + threadIdx.x;   // 0..16383

    if (gt < 1024) {
        int r = gt >> 6;
        float sr = gr[r] * rsqrtf(vr[r] + 1e-5f);
        wsf[OFF_WR + gt] = sr * wred[gt];
    }
    if (gt < 16) {
        float sr = gr[gt] * rsqrtf(vr[gt] + 1e-5f);
        wsf[OFF_CR + gt] = br[gt] - mr[gt] * sr;
    }
    if (gt < 3136) wsf[OFF_WSP + gt] = wspan[gt];
    if (gt < 196)  wsf[OFF_BSP + gt] = bspan[gt];
    if (gt < 64) {
        float si = gi[gt] * rsqrtf(vi[gt] + 1e-5f);
        wsf[OFF_SI + gt] = si;
        wsf[OFF_CI + gt] = bi[gt] - mi[gt] * si;
    }
    if (gt < 128) {
        float sc = gc[gt] * rsqrtf(vc[gt] + 1e-5f);
        float sm = gm[gt] * rsqrtf(vm[gt] + 1e-5f);
        wsf[OFF_BIAS + gt] = (bc[gt] - mc[gt] * sc)
                           + sm * bmap[gt]
                           + (bm[gt] - mmn[gt] * sm);
    }
    // W MFMA A-fragments: lane l holds W[mt*16+(l&15)][ks*32+(l>>4)*8+j]
    {
        int j    = gt & 7;
        int lane = (gt >> 3) & 63;
        int ks   = (gt >> 9) & 3;
        int mt   = gt >> 11;
        int m = mt * 16 + (lane & 15);
        int k = ks * 32 + (lane >> 4) * 8 + j;
        float v;
        if (k < 64) {
            float sc = gc[m] * rsqrtf(vc[m] + 1e-5f);
            v = sc * wconv[m * 64 + k];
        } else {
            float sm = gm[m] * rsqrtf(vm[m] + 1e-5f);
            v = sm * wmap[m * 64 + (k - 64)];
        }
        wfrag[gt] = __float2bfloat16(v);
    }
}

// ---------------- K1: involution + bn_i + GELU -> x1 (bf16 in ws) ----------
// Block: 256 threads = 64 pixels (8x8 tile) x 4 channel-quads of ONE group.
// Grid (12,12,16), z = b*4 + g.  LDS ~29 KB -> 5 blocks/CU.
__global__ __launch_bounds__(256) void k_inv2(
    const float* __restrict__ x, const float* __restrict__ wsf,
    bf16* __restrict__ x1)
{
    __shared__ float xs4[3136];     // [quad4][pos196][ci4]   12544 B
    __shared__ float ks[49 * 64];   // [kk][px]               12544 B
    __shared__ float ts[64 * 17];   // [px][16] t, stride 17   4352 B

    const int tid = threadIdx.x;
    const int bz  = blockIdx.z;
    const int b   = bz >> 2, g = bz & 3;
    const int ty  = blockIdx.y * 8, tx = blockIdx.x * 8;

    const float* xb = x + (size_t)b * 64 * HW;

    // ---- stage own-group 14x14 halo (16 ch, interleaved-4 for b128) ----
    for (int it = tid; it < 784; it += 256) {        // it = qc*196 + pos
        int qc = it / 196, pos = it % 196;
        int py = pos / 14, px = pos % 14;
        int gy = ty + py - 3, gx = tx + px - 3;
        v4f v = (v4f){0.f, 0.f, 0.f, 0.f};
        if (gy >= 0 && gy < HD && gx >= 0 && gx < WD) {
            const float* pp = xb + (size_t)(g * 16 + qc * 4) * HW + gy * WD + gx;
            v[0] = pp[0]; v[1] = pp[HW]; v[2] = pp[2 * HW]; v[3] = pp[3 * HW];
        }
        *(v4f*)&xs4[it * 4] = v;
    }

    // ---- t: thread (p,u) computes t[u*4..u*4+3] at its pixel (global x) ----
    const int p  = tid & 63;
    const int u  = __builtin_amdgcn_readfirstlane(tid >> 6);  // wave-uniform
    const int py0 = p >> 3, px0 = p & 7;
    const int hw  = (ty + py0) * WD + (tx + px0);

    float t4[4];
    #pragma unroll
    for (int r = 0; r < 4; ++r) t4[r] = wsf[OFF_CR + u * 4 + r];
    #pragma unroll 4
    for (int c = 0; c < 64; ++c) {
        float xc = xb[(size_t)c * HW + hw];
        #pragma unroll
        for (int r = 0; r < 4; ++r)
            t4[r] += wsf[OFF_WR + (u * 4 + r) * 64 + c] * xc;
    }
    #pragma unroll
    for (int r = 0; r < 4; ++r) ts[p * 17 + u * 4 + r] = fmaxf(t4[r], 0.0f);
    __syncthreads();

    float tr[16];
    #pragma unroll
    for (int r = 0; r < 16; ++r) tr[r] = ts[p * 17 + r];

    // ---- kern values for this group's 49 offsets -> LDS (once per px) ----
    for (int kk = u; kk < 49; kk += 4) {
        int row = g * 49 + kk;                       // wave-uniform -> s_load
        float kv = wsf[OFF_BSP + row];
        #pragma unroll
        for (int r = 0; r < 16; ++r) kv += wsf[OFF_WSP + row * 16 + r] * tr[r];
        ks[kk * 64 + p] = kv;
    }
    __syncthreads();

    // ---- involution accumulate: 4 channels per thread ----
    float acc[4] = {0.f, 0.f, 0.f, 0.f};
    #pragma unroll 1
    for (int i = 0; i < 7; ++i) {
        const int rowb = (py0 + i) * 14 + px0;
        #pragma unroll
        for (int j = 0; j < 7; ++j) {
            float kv = ks[(i * 7 + j) * 64 + p];
            v4f xv = *(const v4f*)&xs4[(u * 196 + rowb + j) * 4];
            acc[0] += kv * xv[0];
            acc[1] += kv * xv[1];
            acc[2] += kv * xv[2];
            acc[3] += kv * xv[3];
        }
    }

    // ---- bn_i + GELU, store x1 (bf16) ----
    const int c0 = g * 16 + u * 4;
    bf16* x1b = x1 + ((size_t)b * 64 + c0) * HW + hw;
    #pragma unroll
    for (int ci = 0; ci < 4; ++ci) {
        float v = acc[ci] * wsf[OFF_SI + c0 + ci] + wsf[OFF_CI + c0 + ci];
        x1b[(size_t)ci * HW] = __float2bfloat16(geluf(v));
    }
}

// ---------------- K2: 128x128 pointwise GEMM + GELU via MFMA ---------------
#define ZPAD 136
__global__ __launch_bounds__(256) void k_out(
    const float* __restrict__ x, const bf16* __restrict__ x1,
    const float* __restrict__ wsf, const bf16* __restrict__ wfrag,
    float* __restrict__ out)
{
    __shared__ bf16 zl[64 * ZPAD];   // [px][ch] transposed Z tile

    const int tid  = threadIdx.x;
    const int lane = tid & 63;
    const int cw   = tid >> 6;
    const int tile = blockIdx.x * 64;      // never straddles a batch
    const int b    = tile / HW;
    const int hw0  = tile % HW;

    const bf16*  x1b = x1 + (size_t)b * 64 * HW + hw0;
    const float* xb  = x  + (size_t)b * 64 * HW + hw0;

    #pragma unroll
    for (int r = 0; r < 32; ++r) {
        int ch = r * 4 + cw;
        bf16 v;
        if (ch < 64) v = x1b[(size_t)ch * HW + lane];
        else         v = __float2bfloat16(xb[(size_t)(ch - 64) * HW + lane]);
        zl[lane * ZPAD + ch] = v;
    }
    __syncthreads();

    const int n    = lane & 15;
    const int quad = lane >> 4;
    const int pxl  = cw * 16 + n;

    v4f acc[8];
    #pragma unroll
    for (int mt = 0; mt < 8; ++mt) acc[mt] = (v4f){0.f, 0.f, 0.f, 0.f};

    const v8s* wf = (const v8s*)wfrag;
    #pragma unroll
    for (int ks = 0; ks < 4; ++ks) {
        v8s bfrag = *(const v8s*)&zl[pxl * ZPAD + ks * 32 + quad * 8];
        #pragma unroll
        for (int mt = 0; mt < 8; ++mt) {
            v8s afrag = wf[(mt * 4 + ks) * 64 + lane];
            acc[mt] = __builtin_amdgcn_mfma_f32_16x16x32_bf16(afrag, bfrag, acc[mt], 0, 0, 0);
        }
    }

    const int hw = hw0 + pxl;
    #pragma unroll
    for (int mt = 0; mt < 8; ++mt) {
        int m0 = mt * 16 + quad * 4;
        v4f bs = *(const v4f*)&wsf[OFF_BIAS + m0];
        #pragma unroll
        for (int reg = 0; reg < 4; ++reg) {
            float v = acc[mt][reg] + bs[reg];
            out[((size_t)(b * 128 + m0 + reg)) * HW + hw] = geluf(v);
        }
    }
}

// ---------------------------------------------------------------------------
extern "C" void kernel_launch(void* const* d_in, const int* in_sizes, int n_in,
                              void* d_out, int out_size, void* d_ws, size_t ws_size,
                              hipStream_t stream)
{
    const float* x     = (const float*)d_in[0];
    const float* wred  = (const float*)d_in[1];
    const float* gr    = (const float*)d_in[2];
    const float* br    = (const float*)d_in[3];
    const float* mr    = (const float*)d_in[4];
    const float* vr    = (const float*)d_in[5];
    const float* wspan = (const float*)d_in[6];
    const float* bspan = (const float*)d_in[7];
    const float* gi    = (const float*)d_in[8];
    const float* bi    = (const float*)d_in[9];
    const float* mi    = (const float*)d_in[10];
    const float* vi    = (const float*)d_in[11];
    const float* wconv = (const float*)d_in[12];
    const float* gc    = (const float*)d_in[13];
    const float* bc    = (const float*)d_in[14];
    const float* mc    = (const float*)d_in[15];
    const float* vc    = (const float*)d_in[16];
    const float* wmap  = (const float*)d_in[17];
    const float* bmap  = (const float*)d_in[18];
    const float* gm    = (const float*)d_in[19];
    const float* bm    = (const float*)d_in[20];
    const float* mmn   = (const float*)d_in[21];
    const float* vm    = (const float*)d_in[22];

    float* wsf   = (float*)d_ws;
    bf16*  wfrag = (bf16*)((char*)d_ws + WFRAG_BYTE);
    bf16*  x1    = (bf16*)((char*)d_ws + X1_BYTE);
    float* out   = (float*)d_out;

    hipLaunchKernelGGL(k_fold, dim3(64), dim3(256), 0, stream,
                       wred, gr, br, mr, vr, wspan, bspan, gi, bi, mi, vi,
                       wconv, gc, bc, mc, vc, wmap, bmap, gm, bm, mmn, vm,
                       wsf, wfrag);
    hipLaunchKernelGGL(k_inv2, dim3(12, 12, 16), dim3(256), 0, stream, x, wsf, x1);
    hipLaunchKernelGGL(k_out, dim3((BATCH * HW) / 64), dim3(256), 0, stream,
                       x, x1, wsf, wfrag, out);
}

// Round 5
// 159.225 us; speedup vs baseline: 3.9606x; 1.0051x over previous
//
#include <hip/hip_runtime.h>
#include <hip/hip_bf16.h>
#include <math.h>

typedef __hip_bfloat16 bf16;
typedef __attribute__((ext_vector_type(8))) short v8s;   // 8 x bf16
typedef __attribute__((ext_vector_type(4))) short v4s;   // 4 x bf16 (8 B)
typedef __attribute__((ext_vector_type(4))) float v4f;

#define HD 96
#define WD 96
#define HW 9216            // 96*96
#define BATCH 4

// ws float-offset layout
#define OFF_WR    0        // 16x64  scaled w_reduce
#define OFF_CR    1024     // 16     reduce-BN additive
#define OFF_WSP   1040     // 196x16 w_span
#define OFF_BSP   4176     // 196    b_span
#define OFF_SI    4372     // 64     bn_i scale
#define OFF_CI    4436     // 64     bn_i additive
#define OFF_BIAS  4500     // 128    combined bias (fp32)
#define WFRAG_BYTE 18512   // bf16 W MFMA A-fragments: [mt8][ks4][lane64][j8] (32KB)
#define ZT_BYTE   51328    // bf16 zt buffer [B*HW][128]: ch0-63=x1, ch64-127=bf16(x) (9.44MB)

__device__ __forceinline__ float geluf(float v) {
    return 0.5f * v * (1.0f + erff(v * 0.7071067811865475f));
}

// ---------------- K0: fold BN params (64 blocks) ---------------------------
__global__ __launch_bounds__(256) void k_fold(
    const float* __restrict__ wred,
    const float* __restrict__ gr, const float* __restrict__ br,
    const float* __restrict__ mr, const float* __restrict__ vr,
    const float* __restrict__ wspan, const float* __restrict__ bspan,
    const float* __restrict__ gi, const float* __restrict__ bi,
    const float* __restrict__ mi, const float* __restrict__ vi,
    const float* __restrict__ wconv,
    const float* __restrict__ gc, const float* __restrict__ bc,
    const float* __restrict__ mc, const float* __restrict__ vc,
    const float* __restrict__ wmap, const float* __restrict__ bmap,
    const float* __restrict__ gm, const float* __restrict__ bm,
    const float* __restrict__ mmn, const float* __restrict__ vm,
    float* __restrict__ wsf, bf16* __restrict__ wfrag)
{
    const int gt = blockIdx.x * 256 + threadIdx.x;   // 0..16383

    if (gt < 1024) {
        int r = gt >> 6;
        float sr = gr[r] * rsqrtf(vr[r] + 1e-5f);
        wsf[OFF_WR + gt] = sr * wred[gt];
    }
    if (gt < 16) {
        float sr = gr[gt] * rsqrtf(vr[gt] + 1e-5f);
        wsf[OFF_CR + gt] = br[gt] - mr[gt] * sr;
    }
    if (gt < 3136) wsf[OFF_WSP + gt] = wspan[gt];
    if (gt < 196)  wsf[OFF_BSP + gt] = bspan[gt];
    if (gt < 64) {
        float si = gi[gt] * rsqrtf(vi[gt] + 1e-5f);
        wsf[OFF_SI + gt] = si;
        wsf[OFF_CI + gt] = bi[gt] - mi[gt] * si;
    }
    if (gt < 128) {
        float sc = gc[gt] * rsqrtf(vc[gt] + 1e-5f);
        float sm = gm[gt] * rsqrtf(vm[gt] + 1e-5f);
        wsf[OFF_BIAS + gt] = (bc[gt] - mc[gt] * sc)
                           + sm * bmap[gt]
                           + (bm[gt] - mmn[gt] * sm);
    }
    // W MFMA A-fragments: lane l holds W[mt*16+(l&15)][ks*32+(l>>4)*8+j]
    {
        int j    = gt & 7;
        int lane = (gt >> 3) & 63;
        int ks   = (gt >> 9) & 3;
        int mt   = gt >> 11;
        int m = mt * 16 + (lane & 15);
        int k = ks * 32 + (lane >> 4) * 8 + j;
        float v;
        if (k < 64) {
            float sc = gc[m] * rsqrtf(vc[m] + 1e-5f);
            v = sc * wconv[m * 64 + k];
        } else {
            float sm = gm[m] * rsqrtf(vm[m] + 1e-5f);
            v = sm * wmap[m * 64 + (k - 64)];
        }
        wfrag[gt] = __float2bfloat16(v);
    }
}

// ---------------- K1: involution + bn_i + GELU -> zt (B-frag layout) -------
// Block: 256 threads = 64 pixels (8x8 tile) x 4 channel-quads of ONE group.
// Grid (12,12,16), z = b*4 + g.
__global__ __launch_bounds__(256) void k_inv2(
    const float* __restrict__ x, const float* __restrict__ wsf,
    bf16* __restrict__ zt)
{
    __shared__ float xs4[3136];     // [quad4][pos196][ci4]   12544 B
    __shared__ float ks[49 * 64];   // [kk][px]               12544 B
    __shared__ float ts[64 * 17];   // [px][16] t, stride 17   4352 B

    const int tid = threadIdx.x;
    const int bz  = blockIdx.z;
    const int b   = bz >> 2, g = bz & 3;
    const int ty  = blockIdx.y * 8, tx = blockIdx.x * 8;

    const float* xb = x + (size_t)b * 64 * HW;

    // ---- stage own-group 14x14 halo (16 ch, interleaved-4 for b128) ----
    for (int it = tid; it < 784; it += 256) {        // it = qc*196 + pos
        int qc = it / 196, pos = it % 196;
        int py = pos / 14, px = pos % 14;
        int gy = ty + py - 3, gx = tx + px - 3;
        v4f v = (v4f){0.f, 0.f, 0.f, 0.f};
        if (gy >= 0 && gy < HD && gx >= 0 && gx < WD) {
            const float* pp = xb + (size_t)(g * 16 + qc * 4) * HW + gy * WD + gx;
            v[0] = pp[0]; v[1] = pp[HW]; v[2] = pp[2 * HW]; v[3] = pp[3 * HW];
        }
        *(v4f*)&xs4[it * 4] = v;
    }

    // ---- t: thread (p,u) computes t[u*4..u*4+3] at its pixel (global x) ----
    const int p  = tid & 63;
    const int u  = __builtin_amdgcn_readfirstlane(tid >> 6);  // wave-uniform
    const int py0 = p >> 3, px0 = p & 7;
    const int hw  = (ty + py0) * WD + (tx + px0);

    float t4[4];
    #pragma unroll
    for (int r = 0; r < 4; ++r) t4[r] = wsf[OFF_CR + u * 4 + r];
    #pragma unroll 4
    for (int c = 0; c < 64; ++c) {
        float xc = xb[(size_t)c * HW + hw];
        #pragma unroll
        for (int r = 0; r < 4; ++r)
            t4[r] += wsf[OFF_WR + (u * 4 + r) * 64 + c] * xc;
    }
    #pragma unroll
    for (int r = 0; r < 4; ++r) ts[p * 17 + u * 4 + r] = fmaxf(t4[r], 0.0f);
    __syncthreads();

    float tr[16];
    #pragma unroll
    for (int r = 0; r < 16; ++r) tr[r] = ts[p * 17 + r];

    // ---- kern values for this group's 49 offsets -> LDS (once per px) ----
    for (int kk = u; kk < 49; kk += 4) {
        int row = g * 49 + kk;                       // wave-uniform -> s_load
        float kv = wsf[OFF_BSP + row];
        #pragma unroll
        for (int r = 0; r < 16; ++r) kv += wsf[OFF_WSP + row * 16 + r] * tr[r];
        ks[kk * 64 + p] = kv;
    }
    __syncthreads();

    // ---- involution accumulate: 4 channels per thread ----
    float acc[4] = {0.f, 0.f, 0.f, 0.f};
    #pragma unroll 1
    for (int i = 0; i < 7; ++i) {
        const int rowb = (py0 + i) * 14 + px0;
        #pragma unroll
        for (int j = 0; j < 7; ++j) {
            float kv = ks[(i * 7 + j) * 64 + p];
            v4f xv = *(const v4f*)&xs4[(u * 196 + rowb + j) * 4];
            acc[0] += kv * xv[0];
            acc[1] += kv * xv[1];
            acc[2] += kv * xv[2];
            acc[3] += kv * xv[3];
        }
    }

    // ---- bn_i + GELU, pack into zt B-fragment layout ----
    const int c0 = g * 16 + u * 4;
    bf16* ztr = zt + ((size_t)b * HW + hw) * 128;

    v4s pk1;
    #pragma unroll
    for (int ci = 0; ci < 4; ++ci) {
        float v = acc[ci] * wsf[OFF_SI + c0 + ci] + wsf[OFF_CI + c0 + ci];
        pk1[ci] = (short)__bfloat16_as_ushort(__float2bfloat16(geluf(v)));
    }
    *(v4s*)&ztr[c0] = pk1;

    const int center = (py0 + 3) * 14 + (px0 + 3);
    v4f xc = *(const v4f*)&xs4[(u * 196 + center) * 4];
    v4s pk2;
    #pragma unroll
    for (int ci = 0; ci < 4; ++ci)
        pk2[ci] = (short)__bfloat16_as_ushort(__float2bfloat16(xc[ci]));
    *(v4s*)&ztr[64 + c0] = pk2;
}

// ---------------- K2: 128x128 pointwise GEMM + GELU via MFMA ---------------
// No LDS, no barrier: B-frags load直接 from zt (fragment-ready layout).
__global__ __launch_bounds__(256) void k_out2(
    const bf16* __restrict__ zt, const float* __restrict__ wsf,
    const bf16* __restrict__ wfrag, float* __restrict__ out)
{
    const int tid  = threadIdx.x;
    const int lane = tid & 63;
    const int wv   = tid >> 6;
    const int n    = lane & 15;
    const int quad = lane >> 4;

    const int pxg = blockIdx.x * 64 + wv * 16 + n;   // global pixel (incl. batch)
    const int b   = pxg / HW;
    const int hw  = pxg % HW;

    // B fragments: zt row is 128 bf16 = 16 v8s; frag(ks) = v8s index ks*4+quad
    const v8s* zb = (const v8s*)(zt + (size_t)pxg * 128);
    v8s bfr[4];
    #pragma unroll
    for (int ks = 0; ks < 4; ++ks) bfr[ks] = zb[ks * 4 + quad];

    const v8s* wf = (const v8s*)wfrag;
    v4f acc[8];
    #pragma unroll
    for (int mt = 0; mt < 8; ++mt) acc[mt] = (v4f){0.f, 0.f, 0.f, 0.f};

    #pragma unroll
    for (int ks = 0; ks < 4; ++ks) {
        #pragma unroll
        for (int mt = 0; mt < 8; ++mt) {
            v8s afrag = wf[(mt * 4 + ks) * 64 + lane];
            acc[mt] = __builtin_amdgcn_mfma_f32_16x16x32_bf16(afrag, bfr[ks], acc[mt], 0, 0, 0);
        }
    }

    #pragma unroll
    for (int mt = 0; mt < 8; ++mt) {
        int m0 = mt * 16 + quad * 4;
        v4f bs = *(const v4f*)&wsf[OFF_BIAS + m0];
        #pragma unroll
        for (int reg = 0; reg < 4; ++reg) {
            float v = acc[mt][reg] + bs[reg];
            out[((size_t)(b * 128 + m0 + reg)) * HW + hw] = geluf(v);
        }
    }
}

// ---------------------------------------------------------------------------
extern "C" void kernel_launch(void* const* d_in, const int* in_sizes, int n_in,
                              void* d_out, int out_size, void* d_ws, size_t ws_size,
                              hipStream_t stream)
{
    const float* x     = (const float*)d_in[0];
    const float* wred  = (const float*)d_in[1];
    const float* gr    = (const float*)d_in[2];
    const float* br    = (const float*)d_in[3];
    const float* mr    = (const float*)d_in[4];
    const float* vr    = (const float*)d_in[5];
    const float* wspan = (const float*)d_in[6];
    const float* bspan = (const float*)d_in[7];
    const float* gi    = (const float*)d_in[8];
    const float* bi    = (const float*)d_in[9];
    const float* mi    = (const float*)d_in[10];
    const float* vi    = (const float*)d_in[11];
    const float* wconv = (const float*)d_in[12];
    const float* gc    = (const float*)d_in[13];
    const float* bc    = (const float*)d_in[14];
    const float* mc    = (const float*)d_in[15];
    const float* vc    = (const float*)d_in[16];
    const float* wmap  = (const float*)d_in[17];
    const float* bmap  = (const float*)d_in[18];
    const float* gm    = (const float*)d_in[19];
    const float* bm    = (const float*)d_in[20];
    const float* mmn   = (const float*)d_in[21];
    const float* vm    = (const float*)d_in[22];

    float* wsf   = (float*)d_ws;
    bf16*  wfrag = (bf16*)((char*)d_ws + WFRAG_BYTE);
    bf16*  zt    = (bf16*)((char*)d_ws + ZT_BYTE);
    float* out   = (float*)d_out;

    hipLaunchKernelGGL(k_fold, dim3(64), dim3(256), 0, stream,
                       wred, gr, br, mr, vr, wspan, bspan, gi, bi, mi, vi,
                       wconv, gc, bc, mc, vc, wmap, bmap, gm, bm, mmn, vm,
                       wsf, wfrag);
    hipLaunchKernelGGL(k_inv2, dim3(12, 12, 16), dim3(256), 0, stream, x, wsf, zt);
    hipLaunchKernelGGL(k_out2, dim3((BATCH * HW) / 64), dim3(256), 0, stream,
                       zt, wsf, wfrag, out);
}